// Round 1
// baseline (3942.815 us; speedup 1.0000x reference)
//
#include <hip/hip_runtime.h>
#include <hip/hip_bf16.h>
#include <math.h>

#define DEV __device__ __forceinline__

DEV float wsum64(float v){
  #pragma unroll
  for (int off = 32; off; off >>= 1) v += __shfl_xor(v, off, 64);
  return v;
}
DEV float geluf(float x){
  return 0.5f*x*(1.f + tanhf(0.7978845608028654f*(x + 0.044715f*x*x*x)));
}
DEV float gelu_bwdf(float x){
  float x2 = x*x;
  float t = tanhf(0.79788456f*x*(1.f + 0.044715f*x2));
  return 0.5f*x*((1.f - t*t)*(0.79788456f + 0.1070322243f*x2)) + 0.5f*(1.f + t);
}
DEV float sigmf(float x){ return 1.f/(1.f + expf(-x)); }

// ---------------------------------------------------------------------------
// Stem conv s11: x[512,3,96,96] -> conv7x7 s2 p3 -> BN -> ReLU -> maxpool2 -> xs[512,8,24,24]
// thread: one pooled position, all 8 channels. grid 1152 x 256.
__global__ __launch_bounds__(256) void k_s11(const float* __restrict__ x,
    const float* __restrict__ w, const float* __restrict__ bias,
    const float* __restrict__ bn, float* __restrict__ xs){
  __shared__ float ws[8*3*49];
  for (int i = threadIdx.x; i < 8*3*49; i += 256) ws[i] = w[i];
  __syncthreads();
  int gid = blockIdx.x*256 + threadIdx.x;
  int bd = gid/576, pos = gid - bd*576;
  int ph = pos/24, pw = pos - ph*24;
  const float* xb = x + (size_t)bd*3*9216;
  float acc[4][8];
  #pragma unroll
  for (int p=0;p<4;p++){
    #pragma unroll
    for (int c=0;c<8;c++) acc[p][c]=0.f;
  }
  for (int ci=0; ci<3; ci++){
    const float* xc = xb + ci*9216;
    for (int kh=0; kh<7; kh++){
      for (int kw=0; kw<7; kw++){
        float wv[8];
        #pragma unroll
        for (int c=0;c<8;c++) wv[c] = ws[(c*3+ci)*49 + kh*7 + kw];
        #pragma unroll
        for (int p=0;p<4;p++){
          int oh = 2*ph + (p>>1), ow = 2*pw + (p&1);
          int ih = 2*oh - 3 + kh, iw2 = 2*ow - 3 + kw;
          float v = 0.f;
          if (ih>=0 && ih<96 && iw2>=0 && iw2<96) v = xc[ih*96 + iw2];
          #pragma unroll
          for (int c=0;c<8;c++) acc[p][c] += v*wv[c];
        }
      }
    }
  }
  #pragma unroll
  for (int c=0;c<8;c++){
    float g=bn[c], be=bn[8+c], m=bn[16+c], vv=bn[24+c];
    float s = g*rsqrtf(vv + 1e-5f);
    float mx = 0.f;  // relu floor
    #pragma unroll
    for (int p=0;p<4;p++){
      float y = (acc[p][c] + bias[c] - m)*s + be;
      mx = fmaxf(mx, y);
    }
    xs[((size_t)bd*8 + c)*576 + pos] = mx;
  }
}

// Stem conv s12 on frame-diffs (computed on the fly). -> xd[512,8,24,24]
__global__ __launch_bounds__(256) void k_s12(const float* __restrict__ x,
    const float* __restrict__ w, const float* __restrict__ bias,
    const float* __restrict__ bn, float* __restrict__ xd){
  __shared__ float ws[8*12*49];
  for (int i = threadIdx.x; i < 8*12*49; i += 256) ws[i] = w[i];
  __syncthreads();
  int gid = blockIdx.x*256 + threadIdx.x;
  int bd = gid/576, pos = gid - bd*576;
  int ph = pos/24, pw = pos - ph*24;
  int b = bd >> 8, dd = bd & 255;
  int fa[4], fb[4];
  fa[0] = dd>=2 ? dd-1 : 0;    fb[0] = dd>=2 ? dd-2 : 0;
  fa[1] = dd;                  fb[1] = dd>=1 ? dd-1 : 0;
  fa[2] = dd<=254 ? dd+1 : 255; fb[2] = dd;
  fa[3] = dd<=253 ? dd+2 : 255; fb[3] = dd<=254 ? dd+1 : 255;
  float acc[4][8];
  #pragma unroll
  for (int p=0;p<4;p++){
    #pragma unroll
    for (int c=0;c<8;c++) acc[p][c]=0.f;
  }
  for (int g4=0; g4<4; g4++){
    if (fa[g4] == fb[g4]) continue;  // identical frames -> zero diff
    for (int rgb=0; rgb<3; rgb++){
      int ci = g4*3 + rgb;
      const float* xa = x + ((size_t)(b*256 + fa[g4])*3 + rgb)*9216;
      const float* xbp= x + ((size_t)(b*256 + fb[g4])*3 + rgb)*9216;
      for (int kh=0; kh<7; kh++){
        for (int kw=0; kw<7; kw++){
          float wv[8];
          #pragma unroll
          for (int c=0;c<8;c++) wv[c] = ws[(c*12+ci)*49 + kh*7 + kw];
          #pragma unroll
          for (int p=0;p<4;p++){
            int oh = 2*ph + (p>>1), ow = 2*pw + (p&1);
            int ih = 2*oh - 3 + kh, iw2 = 2*ow - 3 + kw;
            float v = 0.f;
            if (ih>=0 && ih<96 && iw2>=0 && iw2<96){
              int off = ih*96 + iw2;
              v = xa[off] - xbp[off];
            }
            #pragma unroll
            for (int c=0;c<8;c++) acc[p][c] += v*wv[c];
          }
        }
      }
    }
  }
  #pragma unroll
  for (int c=0;c<8;c++){
    float g=bn[c], be=bn[8+c], m=bn[16+c], vv=bn[24+c];
    float s = g*rsqrtf(vv + 1e-5f);
    float mx = 0.f;
    #pragma unroll
    for (int p=0;p<4;p++){
      float y = (acc[p][c] + bias[c] - m)*s + be;
      mx = fmaxf(mx, y);
    }
    xd[((size_t)bd*8 + c)*576 + pos] = mx;
  }
}

// s21/s22: in = 0.5*(A+B) [512,8,24,24] -> conv7x7 s1 p3 -> BN relu pool -> [512,16,12,12]
// thread: one pooled pos, 8 of 16 channels. grid 576 x 256.
__global__ __launch_bounds__(256) void k_s2x(const float* __restrict__ inA,
    const float* __restrict__ inB, const float* __restrict__ w,
    const float* __restrict__ bias, const float* __restrict__ bn,
    float* __restrict__ outp){
  __shared__ float ws[16*8*49];
  for (int i = threadIdx.x; i < 6272; i += 256) ws[i] = w[i];
  __syncthreads();
  int gid = blockIdx.x*256 + threadIdx.x;
  int bd = gid/288;
  int rem = gid - bd*288;
  int half = rem/144;
  int pos = rem - half*144;
  int ph = pos/12, pw = pos - ph*12;
  const float* pa = inA + (size_t)bd*8*576;
  const float* pb = inB + (size_t)bd*8*576;
  float acc[4][8];
  #pragma unroll
  for (int p=0;p<4;p++){
    #pragma unroll
    for (int c=0;c<8;c++) acc[p][c]=0.f;
  }
  for (int ci=0; ci<8; ci++){
    const float* ia = pa + ci*576;
    const float* ib = pb + ci*576;
    for (int kh=0; kh<7; kh++){
      for (int kw=0; kw<7; kw++){
        float wv[8];
        #pragma unroll
        for (int c=0;c<8;c++) wv[c] = ws[((half*8+c)*8+ci)*49 + kh*7 + kw];
        #pragma unroll
        for (int p=0;p<4;p++){
          int oh = 2*ph + (p>>1), ow = 2*pw + (p&1);
          int ih = oh - 3 + kh, iw2 = ow - 3 + kw;
          float v = 0.f;
          if (ih>=0 && ih<24 && iw2>=0 && iw2<24){
            int off = ih*24 + iw2;
            v = 0.5f*(ia[off] + ib[off]);
          }
          #pragma unroll
          for (int c=0;c<8;c++) acc[p][c] += v*wv[c];
        }
      }
    }
  }
  #pragma unroll
  for (int c=0;c<8;c++){
    int c2 = half*8 + c;
    float g=bn[c2], be=bn[16+c2], m=bn[32+c2], vv=bn[48+c2];
    float s = g*rsqrtf(vv + 1e-5f);
    float mx = 0.f;
    #pragma unroll
    for (int p=0;p<4;p++){
      float y = (acc[p][c] + bias[c2] - m)*s + be;
      mx = fmaxf(mx, y);
    }
    outp[((size_t)bd*16 + c2)*144 + pos] = mx;
  }
}

// s3 conv3x3 p1 + BN + attention-mask pooled signal. block per bd. -> sig[512,64]
__global__ __launch_bounds__(256) void k_s3(const float* __restrict__ p1,
    const float* __restrict__ p2, const float* __restrict__ w,
    const float* __restrict__ bias, const float* __restrict__ bn,
    float* __restrict__ sig){
  __shared__ float ins[16*14*14];
  __shared__ float wT[144*64];
  __shared__ float redS[64*4];
  __shared__ float redF[64*4];
  int bd = blockIdx.x;
  int t = threadIdx.x;
  for (int i = t; i < 16*196; i += 256){
    int ci = i/196, r = i - ci*196, y = r/14, xx = r - y*14;
    float v = 0.f;
    if (y>=1 && y<=12 && xx>=1 && xx<=12){
      size_t idx = ((size_t)bd*16 + ci)*144 + (y-1)*12 + (xx-1);
      v = 0.5f*(p1[idx] + p2[idx]);
    }
    ins[i] = v;
  }
  for (int i = t; i < 9216; i += 256){
    int c = i & 63, k = i >> 6;
    wT[i] = w[c*144 + k];
  }
  __syncthreads();
  int c = t & 63, pg = t >> 6;
  float acc[36];
  #pragma unroll
  for (int pp=0;pp<36;pp++) acc[pp]=0.f;
  for (int k=0; k<144; k++){
    int ci = k/9, kk = k - ci*9, kh = kk/3, kw = kk - kh*3;
    float wv = wT[k*64 + c];
    const float* ip = &ins[ci*196];
    #pragma unroll
    for (int pp=0;pp<36;pp++){
      int y = pg*3 + pp/12, xx = pp%12;
      acc[pp] += ip[(y+kh)*14 + (xx+kw)] * wv;
    }
  }
  float g=bn[c], be=bn[64+c], m=bn[128+c], vv=bn[192+c];
  float s = g*rsqrtf(vv + 1e-5f);
  float bi = bias[c];
  float sS = 0.f, sF = 0.f;
  #pragma unroll
  for (int pp=0;pp<36;pp++){
    float f = (acc[pp] + bi - m)*s + be;
    float sg = sigmf(f);
    sS += sg; sF += f*sg;
  }
  redS[c*4+pg] = sS; redF[c*4+pg] = sF;
  __syncthreads();
  if (t < 64){
    float S = redS[t*4]+redS[t*4+1]+redS[t*4+2]+redS[t*4+3];
    float F = redF[t*4]+redF[t*4+1]+redF[t*4+2]+redF[t*4+3];
    sig[(size_t)bd*64 + t] = 0.5f*F/S;
  }
}

// c1 1x1 conv: sig[b,t,64] -> h[b,256,256] (channel-major). block=(b,o). grid 512.
__global__ __launch_bounds__(256) void k_c1(const float* __restrict__ sig,
    const float* __restrict__ w, const float* __restrict__ bias,
    float* __restrict__ h){
  int b = blockIdx.x >> 8, o = blockIdx.x & 255, tt = threadIdx.x;
  __shared__ float wl[64];
  if (tt < 64) wl[tt] = w[o*64 + tt];
  __syncthreads();
  const float4* sp = (const float4*)(sig + ((size_t)(b*256 + tt))*64);
  const float4* wp = (const float4*)wl;
  float a = bias[o];
  #pragma unroll
  for (int i=0;i<16;i++){
    float4 s4 = sp[i]; float4 w4 = wp[i];
    a += s4.x*w4.x + s4.y*w4.y + s4.z*w4.z + s4.w*w4.w;
  }
  h[((size_t)b*256 + o)*256 + tt] = fmaxf(a, 0.f);
}

// conv1d 256->256 k3 p1 + relu. mode: 0=none 1=acc:=out 2=acc+=out. grid 256.
__global__ __launch_bounds__(256) void k_conv1d(const float* __restrict__ hin,
    const float* __restrict__ w, const float* __restrict__ bias,
    float* __restrict__ hout, float* __restrict__ accb, int mode){
  __shared__ float ins[256*34];
  __shared__ float ws[16*256*3];
  int bx = blockIdx.x;
  int b = bx >> 7;
  int rem = bx & 127;
  int og = rem >> 3;
  int tg = rem & 7;
  int tid = threadIdx.x;
  int t0 = tg*32;
  for (int idx = tid; idx < 256*34; idx += 256){
    int ii = idx/34, jj = idx - ii*34;
    int tglob = t0 - 1 + jj;
    float v = 0.f;
    if (tglob >= 0 && tglob < 256) v = hin[((size_t)b*256 + ii)*256 + tglob];
    ins[idx] = v;
  }
  for (int idx = tid; idx < 16*256*3; idx += 256)
    ws[idx] = w[(size_t)og*12288 + idx];
  __syncthreads();
  int ol = tid >> 5, tl = tid & 31;
  int o1 = og*16 + ol, o2 = o1 + 8;
  float a1 = bias[o1], a2 = bias[o2];
  const float* w1b = &ws[ol*768];
  const float* w2b = &ws[(ol+8)*768];
  for (int i=0;i<256;i++){
    float v0 = ins[i*34 + tl];
    float v1 = ins[i*34 + tl + 1];
    float v2 = ins[i*34 + tl + 2];
    const float* w1p = w1b + i*3;
    const float* w2p = w2b + i*3;
    a1 += w1p[0]*v0 + w1p[1]*v1 + w1p[2]*v2;
    a2 += w2p[0]*v0 + w2p[1]*v1 + w2p[2]*v2;
  }
  a1 = fmaxf(a1, 0.f); a2 = fmaxf(a2, 0.f);
  size_t i1 = ((size_t)b*256 + o1)*256 + t0 + tl;
  size_t i2 = ((size_t)b*256 + o2)*256 + t0 + tl;
  hout[i1] = a1; hout[i2] = a2;
  if (mode == 1){ accb[i1] = a1; accb[i2] = a2; }
  else if (mode == 2){ accb[i1] += a1; accb[i2] += a2; }
}

// acc[b,c,t] -> transpose + LN(ln_g,ln_b) -> hid[(b t),c]. grid 512.
__global__ __launch_bounds__(256) void k_ln_tr(const float* __restrict__ acc,
    const float* __restrict__ g, const float* __restrict__ be,
    float* __restrict__ hid){
  int b = blockIdx.x >> 8, tt = blockIdx.x & 255, c = threadIdx.x;
  __shared__ float rs[4];
  __shared__ float rq[4];
  float v = acc[((size_t)b*256 + c)*256 + tt];
  float s1 = wsum64(v), s2 = wsum64(v*v);
  int wv = c >> 6, ln = c & 63;
  if (ln == 0){ rs[wv]=s1; rq[wv]=s2; }
  __syncthreads();
  float mu = (rs[0]+rs[1]+rs[2]+rs[3])*(1.f/256.f);
  float msq = (rq[0]+rq[1]+rq[2]+rq[3])*(1.f/256.f);
  float var = msq - mu*mu;
  hid[(size_t)blockIdx.x*256 + c] = (v-mu)*rsqrtf(var + 1e-5f)*g[c] + be[c];
}

// projections hid @ {wq,wk,wv}. grid 1536.
__global__ __launch_bounds__(256) void k_proj(const float* __restrict__ hid,
    const float* __restrict__ wq, const float* __restrict__ wk,
    const float* __restrict__ wv, float* __restrict__ xq,
    float* __restrict__ xk, float* __restrict__ xv){
  int m = blockIdx.x >> 9, row = blockIdx.x & 511, c = threadIdx.x;
  const float* W = (m==0) ? wq : ((m==1) ? wk : wv);
  float* O = (m==0) ? xq : ((m==1) ? xk : xv);
  __shared__ float hrow[256];
  hrow[c] = hid[(size_t)row*256 + c];
  __syncthreads();
  float a = 0.f;
  for (int k=0;k<256;k++) a += hrow[k]*W[(size_t)k*256 + c];
  O[(size_t)row*256 + c] = a;
}

// eta_lr (scaled): 0.1*sigmoid(hid.lr_w + lr_b)/64. grid 8 (b*4+h).
__global__ __launch_bounds__(256) void k_eta(const float* __restrict__ hid,
    const float* __restrict__ lrw, const float* __restrict__ lrb,
    float* __restrict__ etalr){
  int b = blockIdx.x >> 2, h = blockIdx.x & 3, l = threadIdx.x;
  const float* hp = hid + ((size_t)(b*256 + l))*256;
  float a = lrb[h];
  for (int k=0;k<256;k++) a += hp[k]*lrw[h*256 + k];
  etalr[(size_t)blockIdx.x*256 + l] = 0.1f*sigmf(a)*(1.f/64.f);
}

// TTT-MLP scan. One block per (b,h). 64 sequential steps.
__global__ __launch_bounds__(256) void k_ttt(
    const float* __restrict__ xq, const float* __restrict__ xk,
    const float* __restrict__ xv, const float* __restrict__ etalr,
    const float* __restrict__ tib, const float* __restrict__ lnw,
    const float* __restrict__ lnb, const float* __restrict__ W1g,
    const float* __restrict__ B1g, const float* __restrict__ W2g,
    const float* __restrict__ B2g, float* __restrict__ out){
  __shared__ float W1s[64*256];      // [d][j]
  __shared__ float W2Ts[64*257];     // [c][r] = W2[r][c], pad 257
  __shared__ float b1s[256];
  __shared__ float b2s[64];
  __shared__ float gs[64];
  __shared__ float bs[64];
  __shared__ float qs[256];
  __shared__ float ks[256];
  __shared__ float vs[256];
  __shared__ float x2s[4*256];
  __shared__ float x2bs[4*256];
  __shared__ float gz2s[4*64];
  __shared__ float coef[16];
  __shared__ float coef2[16];
  __shared__ float els[4];
  __shared__ float les[4];
  __shared__ float toks[4];

  int b = blockIdx.x >> 2, h = blockIdx.x & 3;
  int j = threadIdx.x;
  int iw = j >> 6, cl = j & 63;

  for (int i=j; i<16384; i+=256) W1s[i] = W1g[(size_t)h*16384 + i];
  for (int i=j; i<16384; i+=256){
    int r = i >> 6, c = i & 63;
    W2Ts[c*257 + r] = W2g[(size_t)h*16384 + i];
  }
  b1s[j] = B1g[h*256 + j];
  if (j < 64){ b2s[j] = B2g[h*64 + j]; gs[j] = lnw[h*64 + j]; bs[j] = lnb[h*64 + j]; }
  if (j < 4) toks[j] = fmaxf(1.f/(float)(j+1) + tib[j], 0.f);
  __syncthreads();

  const float* xqp = xq + (size_t)b*65536 + h*64;
  const float* xkp = xk + (size_t)b*65536 + h*64;
  const float* xvp = xv + (size_t)b*65536 + h*64;
  const float* ep  = etalr + (size_t)(b*4 + h)*256;

  for (int n=0; n<64; n++){
    // P1: stage q,k,v, eta row
    {
      int l = n*4 + iw;
      qs[j] = xqp[(size_t)l*256 + cl];
      ks[j] = xkp[(size_t)l*256 + cl];
      vs[j] = xvp[(size_t)l*256 + cl];
      if (j < 4){ float e = ep[n*4 + j]; els[j] = e; les[j] = toks[3]*e; }
    }
    __syncthreads();
    // P2: Z1 = k@W1+b1, qW1 = q@W1+b1, X2 = gelu(Z1); A1->coef
    float z1v[4], qw[4];
    #pragma unroll
    for (int i=0;i<4;i++){ z1v[i] = b1s[j]; qw[i] = b1s[j]; }
    for (int d=0; d<64; d++){
      float wv = W1s[d*256 + j];
      #pragma unroll
      for (int i=0;i<4;i++){
        z1v[i] += ks[i*64 + d]*wv;
        qw[i]  += qs[i*64 + d]*wv;
      }
    }
    float x2o[4];
    #pragma unroll
    for (int i=0;i<4;i++){ x2o[i] = geluf(z1v[i]); x2s[i*256 + j] = x2o[i]; }
    if (j < 16){
      int i = j >> 2, r = j & 3;
      float cv = 0.f;
      if (r <= i){
        float a = 0.f;
        for (int d=0; d<64; d++) a += qs[i*64+d]*ks[r*64+d];
        cv = toks[i]*els[r]*(a + 1.f);
      }
      coef[j] = cv;
    }
    __syncthreads();
    // P3: Z2 = X2@W2+b2 (thread=(iw,cl)), gZ2 = ln_l2_bwd
    float z2 = b2s[cl];
    {
      const float* xr = &x2s[iw*256];
      const float* wr = &W2Ts[cl*257];
      for (int d=0; d<256; d++) z2 += xr[d]*wr[d];
    }
    float mu = wsum64(z2)*(1.f/64.f);
    float df = z2 - mu;
    float var = wsum64(df*df)*(1.f/64.f);
    float stdv = sqrtf(var + 1e-6f);
    float xhat = df/stdv;
    float tgt = vs[j] - ks[j];
    float gxh = (gs[cl]*xhat + bs[cl] - tgt)*gs[cl];
    float sg1 = wsum64(gxh);
    float sg2 = wsum64(gxh*xhat);
    float gz2 = (64.f*gxh - sg1 - xhat*sg2)*(1.f/(64.f*stdv));
    gz2s[j] = gz2;
    __syncthreads();
    // P4: gZ1 = (gZ2@W2^T)*gelu'(Z1); Z1b; X2b
    float gd[4] = {0.f,0.f,0.f,0.f};
    for (int d2=0; d2<64; d2++){
      float wv = W2Ts[d2*257 + j];
      #pragma unroll
      for (int i=0;i<4;i++) gd[i] += gz2s[i*64 + d2]*wv;
    }
    float gz1[4], x2bo[4];
    #pragma unroll
    for (int i=0;i<4;i++) gz1[i] = gd[i]*gelu_bwdf(z1v[i]);
    #pragma unroll
    for (int i=0;i<4;i++){
      float zb = qw[i];
      #pragma unroll
      for (int r=0;r<4;r++) zb -= coef[i*4 + r]*gz1[r];
      x2bo[i] = geluf(zb);
      x2bs[i*256 + j] = x2bo[i];
    }
    __syncthreads();
    // P5a: A2 -> coef2
    if (j < 16){
      int i = j >> 2, r = j & 3;
      float cv = 0.f;
      if (r <= i){
        float a = 0.f;
        for (int d=0; d<256; d++) a += x2bs[i*256+d]*x2s[r*256+d];
        cv = toks[i]*els[r]*(a + 1.f);
      }
      coef2[j] = cv;
    }
    __syncthreads();
    // P5b: Z2b, ln_fwd, output
    float z2b = b2s[cl];
    {
      const float* xr = &x2bs[iw*256];
      const float* wr = &W2Ts[cl*257];
      for (int d=0; d<256; d++) z2b += xr[d]*wr[d];
    }
    #pragma unroll
    for (int r=0;r<4;r++) z2b -= coef2[iw*4 + r]*gz2s[r*64 + cl];
    float mu2 = wsum64(z2b)*(1.f/64.f);
    float df2 = z2b - mu2;
    float var2 = wsum64(df2*df2)*(1.f/64.f);
    float lnv = gs[cl]*df2*rsqrtf(var2 + 1e-6f) + bs[cl];
    out[((size_t)b*256 + n*4 + iw)*256 + h*64 + cl] = qs[j] + lnv;
    __syncthreads();
    // P6: state updates
    float lg1[4], lx[4];
    #pragma unroll
    for (int i=0;i<4;i++){ lg1[i] = les[i]*gz1[i]; lx[i] = les[i]*x2bo[i]; }
    for (int d=0; d<64; d++){
      float wv = W1s[d*256 + j];
      #pragma unroll
      for (int i=0;i<4;i++) wv -= lg1[i]*ks[i*64 + d];
      W1s[d*256 + j] = wv;
    }
    b1s[j] -= lg1[0]+lg1[1]+lg1[2]+lg1[3];
    for (int c2=0; c2<64; c2++){
      float wv = W2Ts[c2*257 + j];
      #pragma unroll
      for (int i=0;i<4;i++) wv -= lx[i]*gz2s[i*64 + c2];
      W2Ts[c2*257 + j] = wv;
    }
    if (j < 64){
      float bb = b2s[j];
      #pragma unroll
      for (int i=0;i<4;i++) bb -= les[i]*gz2s[i*64 + j];
      b2s[j] = bb;
    }
    __syncthreads();
  }
}

// Fused head: LN(post) -> @wo -> LN(ln) -> fc1 -> fc2 -> fc3. grid 512 rows.
__global__ __launch_bounds__(256) void k_head(const float* __restrict__ hid2,
    const float* __restrict__ pg, const float* __restrict__ pb,
    const float* __restrict__ wo, const float* __restrict__ lg,
    const float* __restrict__ lb, const float* __restrict__ fcw,
    const float* __restrict__ fcb, const float* __restrict__ fc2w,
    const float* __restrict__ fc2b, const float* __restrict__ fc3w,
    const float* __restrict__ fc3b, float* __restrict__ outp){
  int row = blockIdx.x, c = threadIdx.x;
  __shared__ float t1[256];
  __shared__ float t3[256];
  __shared__ float t4[128];
  __shared__ float t5[64];
  __shared__ float rs[4];
  __shared__ float rq[4];
  int wv = c >> 6, ln = c & 63;
  float v = hid2[(size_t)row*256 + c];
  float s1 = wsum64(v), s2 = wsum64(v*v);
  if (ln == 0){ rs[wv]=s1; rq[wv]=s2; }
  __syncthreads();
  float mu = (rs[0]+rs[1]+rs[2]+rs[3])*(1.f/256.f);
  float msq = (rq[0]+rq[1]+rq[2]+rq[3])*(1.f/256.f);
  float var = msq - mu*mu;
  t1[c] = (v-mu)*rsqrtf(var + 1e-5f)*pg[c] + pb[c];
  __syncthreads();
  float a = 0.f;
  for (int k=0;k<256;k++) a += t1[k]*wo[(size_t)k*256 + c];
  float u1 = wsum64(a), u2 = wsum64(a*a);
  if (ln == 0){ rs[wv]=u1; rq[wv]=u2; }
  __syncthreads();
  mu = (rs[0]+rs[1]+rs[2]+rs[3])*(1.f/256.f);
  msq = (rq[0]+rq[1]+rq[2]+rq[3])*(1.f/256.f);
  var = msq - mu*mu;
  t3[c] = (a-mu)*rsqrtf(var + 1e-5f)*lg[c] + lb[c];
  __syncthreads();
  if (c < 128){
    float s = fcb[c];
    for (int k=0;k<256;k++) s += t3[k]*fcw[(size_t)k*128 + c];
    t4[c] = s;
  }
  __syncthreads();
  if (c < 64){
    float s = fc2b[c];
    for (int k=0;k<128;k++) s += t4[k]*fc2w[(size_t)k*64 + c];
    t5[c] = s;
  }
  __syncthreads();
  if (c < 64){
    float p = t5[c]*fc3w[c];
    p = wsum64(p);
    if (c == 0) outp[row] = p + fc3b[0];
  }
}

extern "C" void kernel_launch(void* const* d_in, const int* in_sizes, int n_in,
                              void* d_out, int out_size, void* d_ws, size_t ws_size,
                              hipStream_t stream){
  (void)in_sizes; (void)n_in; (void)out_size; (void)ws_size;
  const float* x       = (const float*)d_in[0];
  const float* s11_w   = (const float*)d_in[1];
  const float* s11_b   = (const float*)d_in[2];
  const float* bn11    = (const float*)d_in[3];
  const float* s12_w   = (const float*)d_in[4];
  const float* s12_b   = (const float*)d_in[5];
  const float* bn12    = (const float*)d_in[6];
  const float* s21_w   = (const float*)d_in[7];
  const float* s21_b   = (const float*)d_in[8];
  const float* bn21    = (const float*)d_in[9];
  const float* s22_w   = (const float*)d_in[10];
  const float* s22_b   = (const float*)d_in[11];
  const float* bn22    = (const float*)d_in[12];
  const float* s3_w    = (const float*)d_in[13];
  const float* s3_b    = (const float*)d_in[14];
  const float* bn3     = (const float*)d_in[15];
  const float* c1_w    = (const float*)d_in[16];
  const float* c1_b    = (const float*)d_in[17];
  const float* cb_w    = (const float*)d_in[18];
  const float* cb_b    = (const float*)d_in[19];
  const float* ln_g    = (const float*)d_in[20];
  const float* ln_b    = (const float*)d_in[21];
  const float* wq      = (const float*)d_in[22];
  const float* wk      = (const float*)d_in[23];
  const float* wv      = (const float*)d_in[24];
  const float* wo      = (const float*)d_in[25];
  const float* lr_w    = (const float*)d_in[26];
  const float* lr_b    = (const float*)d_in[27];
  const float* tib     = (const float*)d_in[28];
  const float* tlnw    = (const float*)d_in[29];
  const float* tlnb    = (const float*)d_in[30];
  const float* W1      = (const float*)d_in[31];
  const float* B1      = (const float*)d_in[32];
  const float* W2      = (const float*)d_in[33];
  const float* B2      = (const float*)d_in[34];
  const float* post_g  = (const float*)d_in[35];
  const float* post_b  = (const float*)d_in[36];
  const float* fc_w    = (const float*)d_in[37];
  const float* fc_b    = (const float*)d_in[38];
  const float* fc2_w   = (const float*)d_in[39];
  const float* fc2_b   = (const float*)d_in[40];
  const float* fc3_w   = (const float*)d_in[41];
  const float* fc3_b   = (const float*)d_in[42];

  float* ws = (float*)d_ws;
  float* xs   = ws;                       // 2359296
  float* xd   = ws + 2359296;             // 2359296
  float* p1   = ws + 4718592;             // 1179648
  float* p2   = ws + 5898240;             // 1179648
  float* sig  = ws + 7077888;             // 32768
  float* buf0 = ws + 7110656;             // 131072
  float* buf1 = ws + 7241728;             // 131072
  float* accb = ws + 7372800;             // 131072
  float* hid  = ws + 7503872;             // 131072
  float* xqb  = ws + 7634944;             // 131072
  float* xkb  = ws + 7766016;             // 131072
  float* xvb  = ws + 7897088;             // 131072
  float* eta  = ws + 8028160;             // 2048
  float* hid2 = ws + 8030208;             // 131072

  k_s11<<<1152, 256, 0, stream>>>(x, s11_w, s11_b, bn11, xs);
  k_s12<<<1152, 256, 0, stream>>>(x, s12_w, s12_b, bn12, xd);
  k_s2x<<<576, 256, 0, stream>>>(xs, xd, s21_w, s21_b, bn21, p1);
  k_s2x<<<576, 256, 0, stream>>>(xd, xd, s22_w, s22_b, bn22, p2);
  k_s3<<<512, 256, 0, stream>>>(p1, p2, s3_w, s3_b, bn3, sig);
  k_c1<<<512, 256, 0, stream>>>(sig, c1_w, c1_b, buf0);
  {
    float* cin = buf0; float* cout = buf1;
    for (int l=0; l<8; l++){
      int mode = (l == 1) ? 1 : ((l & 1) ? 2 : 0);
      k_conv1d<<<256, 256, 0, stream>>>(cin, cb_w + (size_t)l*196608,
                                        cb_b + l*256, cout, accb, mode);
      float* tmp = cin; cin = cout; cout = tmp;
    }
  }
  k_ln_tr<<<512, 256, 0, stream>>>(accb, ln_g, ln_b, hid);
  k_proj<<<1536, 256, 0, stream>>>(hid, wq, wk, wv, xqb, xkb, xvb);
  k_eta<<<8, 256, 0, stream>>>(hid, lr_w, lr_b, eta);
  k_ttt<<<8, 256, 0, stream>>>(xqb, xkb, xvb, eta, tib, tlnw, tlnb,
                               W1, B1, W2, B2, hid2);
  k_head<<<512, 256, 0, stream>>>(hid2, post_g, post_b, wo, ln_g, ln_b,
                                  fc_w, fc_b, fc2_w, fc2_b, fc3_w, fc3_b,
                                  (float*)d_out);
}

// Round 2
// 2093.745 us; speedup vs baseline: 1.8831x; 1.8831x over previous
//
#include <hip/hip_runtime.h>
#include <hip/hip_bf16.h>
#include <math.h>

#define DEV __device__ __forceinline__

DEV float wsum64(float v){
  #pragma unroll
  for (int off = 32; off; off >>= 1) v += __shfl_xor(v, off, 64);
  return v;
}
DEV float geluf(float x){
  return 0.5f*x*(1.f + tanhf(0.7978845608028654f*(x + 0.044715f*x*x*x)));
}
DEV float gelu_bwdf(float x){
  float x2 = x*x;
  float t = tanhf(0.79788456f*x*(1.f + 0.044715f*x2));
  return 0.5f*x*((1.f - t*t)*(0.79788456f + 0.1070322243f*x2)) + 0.5f*(1.f + t);
}
DEV float sigmf(float x){ return 1.f/(1.f + expf(-x)); }

// ---------------------------------------------------------------------------
// Stem s11: x[512,3,96,96] -> conv7x7 s2 p3 -> BN -> ReLU -> pool2 -> xs[512,8,24,24]
// Block: (bd, row-group g of 8 pooled rows). 192 threads = 8 pooled rows x 24 cols.
// LDS: phase-split input tile [3][37 rows][2 planes][53], weights [tap][ci][c8].
__global__ __launch_bounds__(192) void k_s11(const float* __restrict__ x,
    const float* __restrict__ w, const float* __restrict__ bias,
    const float* __restrict__ bn, float* __restrict__ xs){
  __shared__ float st[3*37*2*53];   // 11766 floats
  __shared__ float wl[49*3*8];      // 1176
  int bx = blockIdx.x;
  int bd = bx / 3, g = bx - bd*3;
  int t = threadIdx.x;
  for (int e = t; e < 1176; e += 192){
    int tap = e / 24, r = e - tap*24, ci = r >> 3, c = r & 7;
    wl[e] = w[(c*3 + ci)*49 + tap];
  }
  const float* xb = x + (size_t)bd*3*9216;
  for (int e = t; e < 3*37*102; e += 192){
    int ci = e / 3774, r2 = e - ci*3774;
    int ihl = r2 / 102, pi = r2 - ihl*102;
    int ih = ihl + 32*g - 3, iw = pi - 3;
    float v = 0.f;
    if (ih>=0 && ih<96 && iw>=0 && iw<96) v = xb[(size_t)ci*9216 + ih*96 + iw];
    st[((ci*37 + ihl)*2 + (pi&1))*53 + (pi>>1)] = v;
  }
  __syncthreads();
  int pr = t / 24, pc = t - pr*24;
  float a00[8], a01[8], a10[8], a11[8];
  #pragma unroll
  for (int c=0;c<8;c++){ a00[c]=0.f; a01[c]=0.f; a10[c]=0.f; a11[c]=0.f; }
  for (int ci=0; ci<3; ci++){
    for (int kh=0; kh<7; kh++){
      int rb0 = (ci*37 + 4*pr + kh)*106 + 2*pc;
      int rb1 = rb0 + 212;
      #pragma unroll
      for (int kw=0; kw<7; kw++){
        int off = (kw&1)*53 + (kw>>1);
        float v00 = st[rb0+off], v01 = st[rb0+off+1];
        float v10 = st[rb1+off], v11 = st[rb1+off+1];
        const float4* wp = (const float4*)&wl[((kh*7+kw)*3 + ci)*8];
        float wv[8];
        *(float4*)&wv[0] = wp[0]; *(float4*)&wv[4] = wp[1];
        #pragma unroll
        for (int c=0;c<8;c++){
          a00[c] += v00*wv[c]; a01[c] += v01*wv[c];
          a10[c] += v10*wv[c]; a11[c] += v11*wv[c];
        }
      }
    }
  }
  int pos = (g*8 + pr)*24 + pc;
  #pragma unroll
  for (int c=0;c<8;c++){
    float gg=bn[c], be=bn[8+c], m=bn[16+c], vv=bn[24+c];
    float s = gg*rsqrtf(vv + 1e-5f);
    float bi = bias[c];
    float mx = 0.f;
    mx = fmaxf(mx, (a00[c]+bi-m)*s+be);
    mx = fmaxf(mx, (a01[c]+bi-m)*s+be);
    mx = fmaxf(mx, (a10[c]+bi-m)*s+be);
    mx = fmaxf(mx, (a11[c]+bi-m)*s+be);
    xs[((size_t)bd*8 + c)*576 + pos] = mx;
  }
}

// Stem s12: same structure on frame-diffs (4 groups of 3 channels, diff at staging).
__global__ __launch_bounds__(192) void k_s12(const float* __restrict__ x,
    const float* __restrict__ w, const float* __restrict__ bias,
    const float* __restrict__ bn, float* __restrict__ xd){
  __shared__ float st[3*37*2*53];
  __shared__ float wl[49*12*8];     // 4704
  int bx = blockIdx.x;
  int bd = bx / 3, g = bx - bd*3;
  int b = bd >> 8, dd = bd & 255;
  int t = threadIdx.x;
  for (int e = t; e < 4704; e += 192){
    int tap = e / 96, r = e - tap*96, ci = r >> 3, c = r & 7;
    wl[e] = w[(c*12 + ci)*49 + tap];
  }
  int fa[4], fb[4];
  fa[0] = dd>=2 ? dd-1 : 0;     fb[0] = dd>=2 ? dd-2 : 0;
  fa[1] = dd;                   fb[1] = dd>=1 ? dd-1 : 0;
  fa[2] = dd<=254 ? dd+1 : 255; fb[2] = dd;
  fa[3] = dd<=253 ? dd+2 : 255; fb[3] = dd<=254 ? dd+1 : 255;
  int pr = t / 24, pc = t - pr*24;
  float a00[8], a01[8], a10[8], a11[8];
  #pragma unroll
  for (int c=0;c<8;c++){ a00[c]=0.f; a01[c]=0.f; a10[c]=0.f; a11[c]=0.f; }
  for (int g4=0; g4<4; g4++){
    if (fa[g4] == fb[g4]) continue;   // zero diff, uniform per block
    __syncthreads();
    const float* xa = x + ((size_t)(b*256 + fa[g4]))*3*9216;
    const float* xbp= x + ((size_t)(b*256 + fb[g4]))*3*9216;
    for (int e = t; e < 3*37*102; e += 192){
      int ci = e / 3774, r2 = e - ci*3774;
      int ihl = r2 / 102, pi = r2 - ihl*102;
      int ih = ihl + 32*g - 3, iw = pi - 3;
      float v = 0.f;
      if (ih>=0 && ih<96 && iw>=0 && iw<96){
        size_t off = (size_t)ci*9216 + ih*96 + iw;
        v = xa[off] - xbp[off];
      }
      st[((ci*37 + ihl)*2 + (pi&1))*53 + (pi>>1)] = v;
    }
    __syncthreads();
    for (int ci=0; ci<3; ci++){
      int gch = g4*3 + ci;
      for (int kh=0; kh<7; kh++){
        int rb0 = (ci*37 + 4*pr + kh)*106 + 2*pc;
        int rb1 = rb0 + 212;
        #pragma unroll
        for (int kw=0; kw<7; kw++){
          int off = (kw&1)*53 + (kw>>1);
          float v00 = st[rb0+off], v01 = st[rb0+off+1];
          float v10 = st[rb1+off], v11 = st[rb1+off+1];
          const float4* wp = (const float4*)&wl[((kh*7+kw)*12 + gch)*8];
          float wv[8];
          *(float4*)&wv[0] = wp[0]; *(float4*)&wv[4] = wp[1];
          #pragma unroll
          for (int c=0;c<8;c++){
            a00[c] += v00*wv[c]; a01[c] += v01*wv[c];
            a10[c] += v10*wv[c]; a11[c] += v11*wv[c];
          }
        }
      }
    }
  }
  int pos = (g*8 + pr)*24 + pc;
  #pragma unroll
  for (int c=0;c<8;c++){
    float gg=bn[c], be=bn[8+c], m=bn[16+c], vv=bn[24+c];
    float s = gg*rsqrtf(vv + 1e-5f);
    float bi = bias[c];
    float mx = 0.f;
    mx = fmaxf(mx, (a00[c]+bi-m)*s+be);
    mx = fmaxf(mx, (a01[c]+bi-m)*s+be);
    mx = fmaxf(mx, (a10[c]+bi-m)*s+be);
    mx = fmaxf(mx, (a11[c]+bi-m)*s+be);
    xd[((size_t)bd*8 + c)*576 + pos] = mx;
  }
}

// s21/s22: in = 0.5*(A+B) [512,8,24,24] -> conv7x7 s1 p3 -> BN relu pool -> [512,16,12,12]
// One block per bd. Whole padded tile [8][30][33] in LDS. Threads 0..143 = pooled pos.
__global__ __launch_bounds__(256) void k_s2x(const float* __restrict__ inA,
    const float* __restrict__ inB, const float* __restrict__ w,
    const float* __restrict__ bias, const float* __restrict__ bn,
    float* __restrict__ outp){
  __shared__ float st[8*30*33];     // 7920
  __shared__ float wl[49*8*16];     // 6272
  int bd = blockIdx.x;
  int t = threadIdx.x;
  for (int e = t; e < 6272; e += 256){
    int tap = e >> 7, r = e & 127, ci = r >> 4, c = r & 15;
    wl[e] = w[(c*8 + ci)*49 + tap];
  }
  const float* pa = inA + (size_t)bd*8*576;
  const float* pb = inB + (size_t)bd*8*576;
  for (int e = t; e < 7920; e += 256){
    int ci = e / 990, r2 = e - ci*990;
    int r = r2 / 33, cc = r2 - r*33;
    int ih = r - 3, iw = cc - 3;
    float v = 0.f;
    if (ih>=0 && ih<24 && iw>=0 && iw<24){
      int off = ci*576 + ih*24 + iw;
      v = 0.5f*(pa[off] + pb[off]);
    }
    st[(ci*30 + r)*33 + cc] = v;
  }
  __syncthreads();
  if (t < 144){
    int pr = t / 12, pc = t - pr*12;
    float a00[16], a01[16], a10[16], a11[16];
    #pragma unroll
    for (int c=0;c<16;c++){ a00[c]=0.f; a01[c]=0.f; a10[c]=0.f; a11[c]=0.f; }
    for (int ci=0; ci<8; ci++){
      for (int kh=0; kh<7; kh++){
        int rb = (ci*30 + 2*pr + kh)*33 + 2*pc;
        #pragma unroll
        for (int kw=0; kw<7; kw++){
          float v00 = st[rb+kw],    v01 = st[rb+kw+1];
          float v10 = st[rb+33+kw], v11 = st[rb+34+kw];
          const float4* wp = (const float4*)&wl[((kh*7+kw)*8 + ci)*16];
          float wv[16];
          *(float4*)&wv[0]  = wp[0]; *(float4*)&wv[4]  = wp[1];
          *(float4*)&wv[8]  = wp[2]; *(float4*)&wv[12] = wp[3];
          #pragma unroll
          for (int c=0;c<16;c++){
            a00[c] += v00*wv[c]; a01[c] += v01*wv[c];
            a10[c] += v10*wv[c]; a11[c] += v11*wv[c];
          }
        }
      }
    }
    #pragma unroll
    for (int c=0;c<16;c++){
      float gg=bn[c], be=bn[16+c], m=bn[32+c], vv=bn[48+c];
      float s = gg*rsqrtf(vv + 1e-5f);
      float bi = bias[c];
      float mx = 0.f;
      mx = fmaxf(mx, (a00[c]+bi-m)*s+be);
      mx = fmaxf(mx, (a01[c]+bi-m)*s+be);
      mx = fmaxf(mx, (a10[c]+bi-m)*s+be);
      mx = fmaxf(mx, (a11[c]+bi-m)*s+be);
      outp[((size_t)bd*16 + c)*144 + pr*12 + pc] = mx;
    }
  }
}

// s3 conv3x3 p1 + BN + attention-mask pooled signal. block per bd. -> sig[512,64]
__global__ __launch_bounds__(256) void k_s3(const float* __restrict__ p1,
    const float* __restrict__ p2, const float* __restrict__ w,
    const float* __restrict__ bias, const float* __restrict__ bn,
    float* __restrict__ sig){
  __shared__ float ins[16*14*14];
  __shared__ float wT[144*64];
  __shared__ float redS[64*4];
  __shared__ float redF[64*4];
  int bd = blockIdx.x;
  int t = threadIdx.x;
  for (int i = t; i < 16*196; i += 256){
    int ci = i/196, r = i - ci*196, y = r/14, xx = r - y*14;
    float v = 0.f;
    if (y>=1 && y<=12 && xx>=1 && xx<=12){
      size_t idx = ((size_t)bd*16 + ci)*144 + (y-1)*12 + (xx-1);
      v = 0.5f*(p1[idx] + p2[idx]);
    }
    ins[i] = v;
  }
  for (int i = t; i < 9216; i += 256){
    int c = i & 63, k = i >> 6;
    wT[i] = w[c*144 + k];
  }
  __syncthreads();
  int c = t & 63, pg = t >> 6;
  float acc[36];
  #pragma unroll
  for (int pp=0;pp<36;pp++) acc[pp]=0.f;
  for (int k=0; k<144; k++){
    int ci = k/9, kk = k - ci*9, kh = kk/3, kw = kk - kh*3;
    float wv = wT[k*64 + c];
    const float* ip = &ins[ci*196];
    #pragma unroll
    for (int pp=0;pp<36;pp++){
      int y = pg*3 + pp/12, xx = pp%12;
      acc[pp] += ip[(y+kh)*14 + (xx+kw)] * wv;
    }
  }
  float g=bn[c], be=bn[64+c], m=bn[128+c], vv=bn[192+c];
  float s = g*rsqrtf(vv + 1e-5f);
  float bi = bias[c];
  float sS = 0.f, sF = 0.f;
  #pragma unroll
  for (int pp=0;pp<36;pp++){
    float f = (acc[pp] + bi - m)*s + be;
    float sg = sigmf(f);
    sS += sg; sF += f*sg;
  }
  redS[c*4+pg] = sS; redF[c*4+pg] = sF;
  __syncthreads();
  if (t < 64){
    float S = redS[t*4]+redS[t*4+1]+redS[t*4+2]+redS[t*4+3];
    float F = redF[t*4]+redF[t*4+1]+redF[t*4+2]+redF[t*4+3];
    sig[(size_t)bd*64 + t] = 0.5f*F/S;
  }
}

// c1 1x1 conv: sig[b,t,64] -> h[b,256,256] (channel-major). block=(b,o). grid 512.
__global__ __launch_bounds__(256) void k_c1(const float* __restrict__ sig,
    const float* __restrict__ w, const float* __restrict__ bias,
    float* __restrict__ h){
  int b = blockIdx.x >> 8, o = blockIdx.x & 255, tt = threadIdx.x;
  __shared__ float wl[64];
  if (tt < 64) wl[tt] = w[o*64 + tt];
  __syncthreads();
  const float4* sp = (const float4*)(sig + ((size_t)(b*256 + tt))*64);
  const float4* wp = (const float4*)wl;
  float a = bias[o];
  #pragma unroll
  for (int i=0;i<16;i++){
    float4 s4 = sp[i]; float4 w4 = wp[i];
    a += s4.x*w4.x + s4.y*w4.y + s4.z*w4.z + s4.w*w4.w;
  }
  h[((size_t)b*256 + o)*256 + tt] = fmaxf(a, 0.f);
}

// conv1d 256->256 k3 p1 + relu. mode: 0=none 1=acc:=out 2=acc+=out. grid 256.
__global__ __launch_bounds__(256) void k_conv1d(const float* __restrict__ hin,
    const float* __restrict__ w, const float* __restrict__ bias,
    float* __restrict__ hout, float* __restrict__ accb, int mode){
  __shared__ float ins[256*34];
  __shared__ float ws[16*256*4];   // padded stride-4 taps
  int bx = blockIdx.x;
  int b = bx >> 7;
  int rem = bx & 127;
  int og = rem >> 3;
  int tg = rem & 7;
  int tid = threadIdx.x;
  int t0 = tg*32;
  for (int idx = tid; idx < 256*34; idx += 256){
    int ii = idx/34, jj = idx - ii*34;
    int tglob = t0 - 1 + jj;
    float v = 0.f;
    if (tglob >= 0 && tglob < 256) v = hin[((size_t)b*256 + ii)*256 + tglob];
    ins[idx] = v;
  }
  for (int idx = tid; idx < 12288; idx += 256){
    int q = idx/3;
    ws[q*4 + (idx - q*3)] = w[(size_t)og*12288 + idx];
  }
  __syncthreads();
  int ol = tid >> 5, tl = tid & 31;
  int o1 = og*16 + ol, o2 = o1 + 8;
  float a1 = bias[o1], a2 = bias[o2];
  const float4* w1q = (const float4*)(ws + (size_t)ol*1024);
  const float4* w2q = (const float4*)(ws + (size_t)(ol+8)*1024);
  for (int i=0;i<256;i++){
    float v0 = ins[i*34 + tl];
    float v1 = ins[i*34 + tl + 1];
    float v2 = ins[i*34 + tl + 2];
    float4 wa = w1q[i];
    float4 wb = w2q[i];
    a1 += wa.x*v0 + wa.y*v1 + wa.z*v2;
    a2 += wb.x*v0 + wb.y*v1 + wb.z*v2;
  }
  a1 = fmaxf(a1, 0.f); a2 = fmaxf(a2, 0.f);
  size_t i1 = ((size_t)b*256 + o1)*256 + t0 + tl;
  size_t i2 = ((size_t)b*256 + o2)*256 + t0 + tl;
  hout[i1] = a1; hout[i2] = a2;
  if (mode == 1){ accb[i1] = a1; accb[i2] = a2; }
  else if (mode == 2){ accb[i1] += a1; accb[i2] += a2; }
}

// acc[b,c,t] -> transpose + LN(ln_g,ln_b) -> hid[(b t),c]. grid 512.
__global__ __launch_bounds__(256) void k_ln_tr(const float* __restrict__ acc,
    const float* __restrict__ g, const float* __restrict__ be,
    float* __restrict__ hid){
  int b = blockIdx.x >> 8, tt = blockIdx.x & 255, c = threadIdx.x;
  __shared__ float rs[4];
  __shared__ float rq[4];
  float v = acc[((size_t)b*256 + c)*256 + tt];
  float s1 = wsum64(v), s2 = wsum64(v*v);
  int wv = c >> 6, ln = c & 63;
  if (ln == 0){ rs[wv]=s1; rq[wv]=s2; }
  __syncthreads();
  float mu = (rs[0]+rs[1]+rs[2]+rs[3])*(1.f/256.f);
  float msq = (rq[0]+rq[1]+rq[2]+rq[3])*(1.f/256.f);
  float var = msq - mu*mu;
  hid[(size_t)blockIdx.x*256 + c] = (v-mu)*rsqrtf(var + 1e-5f)*g[c] + be[c];
}

// projections hid @ {wq,wk,wv}. grid 1536.
__global__ __launch_bounds__(256) void k_proj(const float* __restrict__ hid,
    const float* __restrict__ wq, const float* __restrict__ wk,
    const float* __restrict__ wv, float* __restrict__ xq,
    float* __restrict__ xk, float* __restrict__ xv){
  int m = blockIdx.x >> 9, row = blockIdx.x & 511, c = threadIdx.x;
  const float* W = (m==0) ? wq : ((m==1) ? wk : wv);
  float* O = (m==0) ? xq : ((m==1) ? xk : xv);
  __shared__ float hrow[256];
  hrow[c] = hid[(size_t)row*256 + c];
  __syncthreads();
  float a = 0.f;
  for (int k=0;k<256;k++) a += hrow[k]*W[(size_t)k*256 + c];
  O[(size_t)row*256 + c] = a;
}

// eta_lr (scaled): 0.1*sigmoid(hid.lr_w + lr_b)/64. grid 8 (b*4+h).
__global__ __launch_bounds__(256) void k_eta(const float* __restrict__ hid,
    const float* __restrict__ lrw, const float* __restrict__ lrb,
    float* __restrict__ etalr){
  int b = blockIdx.x >> 2, h = blockIdx.x & 3, l = threadIdx.x;
  const float* hp = hid + ((size_t)(b*256 + l))*256;
  float a = lrb[h];
  for (int k=0;k<256;k++) a += hp[k]*lrw[h*256 + k];
  etalr[(size_t)blockIdx.x*256 + l] = 0.1f*sigmf(a)*(1.f/64.f);
}

// TTT-MLP scan. One block per (b,h). 64 sequential steps.
__global__ __launch_bounds__(256) void k_ttt(
    const float* __restrict__ xq, const float* __restrict__ xk,
    const float* __restrict__ xv, const float* __restrict__ etalr,
    const float* __restrict__ tib, const float* __restrict__ lnw,
    const float* __restrict__ lnb, const float* __restrict__ W1g,
    const float* __restrict__ B1g, const float* __restrict__ W2g,
    const float* __restrict__ B2g, float* __restrict__ out){
  __shared__ float W1s[64*256];      // [d][j]
  __shared__ float W2Ts[64*257];     // [c][r] = W2[r][c], pad 257
  __shared__ float b1s[256];
  __shared__ float b2s[64];
  __shared__ float gs[64];
  __shared__ float bs[64];
  __shared__ float qs[256];
  __shared__ float ks[256];
  __shared__ float vs[256];
  __shared__ float x2s[4*256];
  __shared__ float x2bs[4*256];
  __shared__ float gz2s[4*64];
  __shared__ float coef[16];
  __shared__ float coef2[16];
  __shared__ float els[4];
  __shared__ float les[4];
  __shared__ float toks[4];

  int b = blockIdx.x >> 2, h = blockIdx.x & 3;
  int j = threadIdx.x;
  int iw = j >> 6, cl = j & 63;

  for (int i=j; i<16384; i+=256) W1s[i] = W1g[(size_t)h*16384 + i];
  for (int i=j; i<16384; i+=256){
    int r = i >> 6, c = i & 63;
    W2Ts[c*257 + r] = W2g[(size_t)h*16384 + i];
  }
  b1s[j] = B1g[h*256 + j];
  if (j < 64){ b2s[j] = B2g[h*64 + j]; gs[j] = lnw[h*64 + j]; bs[j] = lnb[h*64 + j]; }
  if (j < 4) toks[j] = fmaxf(1.f/(float)(j+1) + tib[j], 0.f);
  __syncthreads();

  const float* xqp = xq + (size_t)b*65536 + h*64;
  const float* xkp = xk + (size_t)b*65536 + h*64;
  const float* xvp = xv + (size_t)b*65536 + h*64;
  const float* ep  = etalr + (size_t)(b*4 + h)*256;

  for (int n=0; n<64; n++){
    {
      int l = n*4 + iw;
      qs[j] = xqp[(size_t)l*256 + cl];
      ks[j] = xkp[(size_t)l*256 + cl];
      vs[j] = xvp[(size_t)l*256 + cl];
      if (j < 4){ float e = ep[n*4 + j]; els[j] = e; les[j] = toks[3]*e; }
    }
    __syncthreads();
    float z1v[4], qw[4];
    #pragma unroll
    for (int i=0;i<4;i++){ z1v[i] = b1s[j]; qw[i] = b1s[j]; }
    for (int d=0; d<64; d++){
      float wv = W1s[d*256 + j];
      #pragma unroll
      for (int i=0;i<4;i++){
        z1v[i] += ks[i*64 + d]*wv;
        qw[i]  += qs[i*64 + d]*wv;
      }
    }
    float x2o[4];
    #pragma unroll
    for (int i=0;i<4;i++){ x2o[i] = geluf(z1v[i]); x2s[i*256 + j] = x2o[i]; }
    if (j < 16){
      int i = j >> 2, r = j & 3;
      float cv = 0.f;
      if (r <= i){
        float a = 0.f;
        for (int d=0; d<64; d++) a += qs[i*64+d]*ks[r*64+d];
        cv = toks[i]*els[r]*(a + 1.f);
      }
      coef[j] = cv;
    }
    __syncthreads();
    float z2 = b2s[cl];
    {
      const float* xr = &x2s[iw*256];
      const float* wr = &W2Ts[cl*257];
      for (int d=0; d<256; d++) z2 += xr[d]*wr[d];
    }
    float mu = wsum64(z2)*(1.f/64.f);
    float df = z2 - mu;
    float var = wsum64(df*df)*(1.f/64.f);
    float stdv = sqrtf(var + 1e-6f);
    float xhat = df/stdv;
    float tgt = vs[j] - ks[j];
    float gxh = (gs[cl]*xhat + bs[cl] - tgt)*gs[cl];
    float sg1 = wsum64(gxh);
    float sg2 = wsum64(gxh*xhat);
    float gz2 = (64.f*gxh - sg1 - xhat*sg2)*(1.f/(64.f*stdv));
    gz2s[j] = gz2;
    __syncthreads();
    float gd[4] = {0.f,0.f,0.f,0.f};
    for (int d2=0; d2<64; d2++){
      float wv = W2Ts[d2*257 + j];
      #pragma unroll
      for (int i=0;i<4;i++) gd[i] += gz2s[i*64 + d2]*wv;
    }
    float gz1[4], x2bo[4];
    #pragma unroll
    for (int i=0;i<4;i++) gz1[i] = gd[i]*gelu_bwdf(z1v[i]);
    #pragma unroll
    for (int i=0;i<4;i++){
      float zb = qw[i];
      #pragma unroll
      for (int r=0;r<4;r++) zb -= coef[i*4 + r]*gz1[r];
      x2bo[i] = geluf(zb);
      x2bs[i*256 + j] = x2bo[i];
    }
    __syncthreads();
    if (j < 16){
      int i = j >> 2, r = j & 3;
      float cv = 0.f;
      if (r <= i){
        float a = 0.f;
        for (int d=0; d<256; d++) a += x2bs[i*256+d]*x2s[r*256+d];
        cv = toks[i]*els[r]*(a + 1.f);
      }
      coef2[j] = cv;
    }
    __syncthreads();
    float z2b = b2s[cl];
    {
      const float* xr = &x2bs[iw*256];
      const float* wr = &W2Ts[cl*257];
      for (int d=0; d<256; d++) z2b += xr[d]*wr[d];
    }
    #pragma unroll
    for (int r=0;r<4;r++) z2b -= coef2[iw*4 + r]*gz2s[r*64 + cl];
    float mu2 = wsum64(z2b)*(1.f/64.f);
    float df2 = z2b - mu2;
    float var2 = wsum64(df2*df2)*(1.f/64.f);
    float lnv = gs[cl]*df2*rsqrtf(var2 + 1e-6f) + bs[cl];
    out[((size_t)b*256 + n*4 + iw)*256 + h*64 + cl] = qs[j] + lnv;
    __syncthreads();
    float lg1[4], lx[4];
    #pragma unroll
    for (int i=0;i<4;i++){ lg1[i] = les[i]*gz1[i]; lx[i] = les[i]*x2bo[i]; }
    for (int d=0; d<64; d++){
      float wv = W1s[d*256 + j];
      #pragma unroll
      for (int i=0;i<4;i++) wv -= lg1[i]*ks[i*64 + d];
      W1s[d*256 + j] = wv;
    }
    b1s[j] -= lg1[0]+lg1[1]+lg1[2]+lg1[3];
    for (int c2=0; c2<64; c2++){
      float wv = W2Ts[c2*257 + j];
      #pragma unroll
      for (int i=0;i<4;i++) wv -= lx[i]*gz2s[i*64 + c2];
      W2Ts[c2*257 + j] = wv;
    }
    if (j < 64){
      float bb = b2s[j];
      #pragma unroll
      for (int i=0;i<4;i++) bb -= les[i]*gz2s[i*64 + j];
      b2s[j] = bb;
    }
    __syncthreads();
  }
}

// Fused head: LN(post) -> @wo -> LN(ln) -> fc1 -> fc2 -> fc3. grid 512 rows.
__global__ __launch_bounds__(256) void k_head(const float* __restrict__ hid2,
    const float* __restrict__ pg, const float* __restrict__ pb,
    const float* __restrict__ wo, const float* __restrict__ lg,
    const float* __restrict__ lb, const float* __restrict__ fcw,
    const float* __restrict__ fcb, const float* __restrict__ fc2w,
    const float* __restrict__ fc2b, const float* __restrict__ fc3w,
    const float* __restrict__ fc3b, float* __restrict__ outp){
  int row = blockIdx.x, c = threadIdx.x;
  __shared__ float t1[256];
  __shared__ float t3[256];
  __shared__ float t4[128];
  __shared__ float t5[64];
  __shared__ float rs[4];
  __shared__ float rq[4];
  int wv = c >> 6, ln = c & 63;
  float v = hid2[(size_t)row*256 + c];
  float s1 = wsum64(v), s2 = wsum64(v*v);
  if (ln == 0){ rs[wv]=s1; rq[wv]=s2; }
  __syncthreads();
  float mu = (rs[0]+rs[1]+rs[2]+rs[3])*(1.f/256.f);
  float msq = (rq[0]+rq[1]+rq[2]+rq[3])*(1.f/256.f);
  float var = msq - mu*mu;
  t1[c] = (v-mu)*rsqrtf(var + 1e-5f)*pg[c] + pb[c];
  __syncthreads();
  float a = 0.f;
  for (int k=0;k<256;k++) a += t1[k]*wo[(size_t)k*256 + c];
  float u1 = wsum64(a), u2 = wsum64(a*a);
  if (ln == 0){ rs[wv]=u1; rq[wv]=u2; }
  __syncthreads();
  mu = (rs[0]+rs[1]+rs[2]+rs[3])*(1.f/256.f);
  msq = (rq[0]+rq[1]+rq[2]+rq[3])*(1.f/256.f);
  var = msq - mu*mu;
  t3[c] = (a-mu)*rsqrtf(var + 1e-5f)*lg[c] + lb[c];
  __syncthreads();
  if (c < 128){
    float s = fcb[c];
    for (int k=0;k<256;k++) s += t3[k]*fcw[(size_t)k*128 + c];
    t4[c] = s;
  }
  __syncthreads();
  if (c < 64){
    float s = fc2b[c];
    for (int k=0;k<128;k++) s += t4[k]*fc2w[(size_t)k*64 + c];
    t5[c] = s;
  }
  __syncthreads();
  if (c < 64){
    float p = t5[c]*fc3w[c];
    p = wsum64(p);
    if (c == 0) outp[row] = p + fc3b[0];
  }
}

extern "C" void kernel_launch(void* const* d_in, const int* in_sizes, int n_in,
                              void* d_out, int out_size, void* d_ws, size_t ws_size,
                              hipStream_t stream){
  (void)in_sizes; (void)n_in; (void)out_size; (void)ws_size;
  const float* x       = (const float*)d_in[0];
  const float* s11_w   = (const float*)d_in[1];
  const float* s11_b   = (const float*)d_in[2];
  const float* bn11    = (const float*)d_in[3];
  const float* s12_w   = (const float*)d_in[4];
  const float* s12_b   = (const float*)d_in[5];
  const float* bn12    = (const float*)d_in[6];
  const float* s21_w   = (const float*)d_in[7];
  const float* s21_b   = (const float*)d_in[8];
  const float* bn21    = (const float*)d_in[9];
  const float* s22_w   = (const float*)d_in[10];
  const float* s22_b   = (const float*)d_in[11];
  const float* bn22    = (const float*)d_in[12];
  const float* s3_w    = (const float*)d_in[13];
  const float* s3_b    = (const float*)d_in[14];
  const float* bn3     = (const float*)d_in[15];
  const float* c1_w    = (const float*)d_in[16];
  const float* c1_b    = (const float*)d_in[17];
  const float* cb_w    = (const float*)d_in[18];
  const float* cb_b    = (const float*)d_in[19];
  const float* ln_g    = (const float*)d_in[20];
  const float* ln_b    = (const float*)d_in[21];
  const float* wq      = (const float*)d_in[22];
  const float* wk      = (const float*)d_in[23];
  const float* wv      = (const float*)d_in[24];
  const float* wo      = (const float*)d_in[25];
  const float* lr_w    = (const float*)d_in[26];
  const float* lr_b    = (const float*)d_in[27];
  const float* tib     = (const float*)d_in[28];
  const float* tlnw    = (const float*)d_in[29];
  const float* tlnb    = (const float*)d_in[30];
  const float* W1      = (const float*)d_in[31];
  const float* B1      = (const float*)d_in[32];
  const float* W2      = (const float*)d_in[33];
  const float* B2      = (const float*)d_in[34];
  const float* post_g  = (const float*)d_in[35];
  const float* post_b  = (const float*)d_in[36];
  const float* fc_w    = (const float*)d_in[37];
  const float* fc_b    = (const float*)d_in[38];
  const float* fc2_w   = (const float*)d_in[39];
  const float* fc2_b   = (const float*)d_in[40];
  const float* fc3_w   = (const float*)d_in[41];
  const float* fc3_b   = (const float*)d_in[42];

  float* ws = (float*)d_ws;
  float* xs   = ws;                       // 2359296
  float* xd   = ws + 2359296;             // 2359296
  float* p1   = ws + 4718592;             // 1179648
  float* p2   = ws + 5898240;             // 1179648
  float* sig  = ws + 7077888;             // 32768
  float* buf0 = ws + 7110656;             // 131072
  float* buf1 = ws + 7241728;             // 131072
  float* accb = ws + 7372800;             // 131072
  float* hid  = ws + 7503872;             // 131072
  float* xqb  = ws + 7634944;             // 131072
  float* xkb  = ws + 7766016;             // 131072
  float* xvb  = ws + 7897088;             // 131072
  float* eta  = ws + 8028160;             // 2048
  float* hid2 = ws + 8030208;             // 131072

  k_s11<<<1536, 192, 0, stream>>>(x, s11_w, s11_b, bn11, xs);
  k_s12<<<1536, 192, 0, stream>>>(x, s12_w, s12_b, bn12, xd);
  k_s2x<<<512, 256, 0, stream>>>(xs, xd, s21_w, s21_b, bn21, p1);
  k_s2x<<<512, 256, 0, stream>>>(xd, xd, s22_w, s22_b, bn22, p2);
  k_s3<<<512, 256, 0, stream>>>(p1, p2, s3_w, s3_b, bn3, sig);
  k_c1<<<512, 256, 0, stream>>>(sig, c1_w, c1_b, buf0);
  {
    float* cin = buf0; float* cout = buf1;
    for (int l=0; l<8; l++){
      int mode = (l == 1) ? 1 : ((l & 1) ? 2 : 0);
      k_conv1d<<<256, 256, 0, stream>>>(cin, cb_w + (size_t)l*196608,
                                        cb_b + l*256, cout, accb, mode);
      float* tmp = cin; cin = cout; cout = tmp;
    }
  }
  k_ln_tr<<<512, 256, 0, stream>>>(accb, ln_g, ln_b, hid);
  k_proj<<<1536, 256, 0, stream>>>(hid, wq, wk, wv, xqb, xkb, xvb);
  k_eta<<<8, 256, 0, stream>>>(hid, lr_w, lr_b, eta);
  k_ttt<<<8, 256, 0, stream>>>(xqb, xkb, xvb, eta, tib, tlnw, tlnb,
                               W1, B1, W2, B2, hid2);
  k_head<<<512, 256, 0, stream>>>(hid2, post_g, post_b, wo, ln_g, ln_b,
                                  fc_w, fc_b, fc2_w, fc2_b, fc3_w, fc3_b,
                                  (float*)d_out);
}